// Round 9
// baseline (521.874 us; speedup 1.0000x reference)
//
#include <hip/hip_runtime.h>
#include <hip/hip_bf16.h>
#include <math.h>
#include <stdint.h>

#define NTOK 21824
#define NTILES 341          // 64-token tiles
#define NITER 4
#define GRIDX 86            // ceil(NTILES / NITER)

typedef __attribute__((ext_vector_type(8)))  short bf16x8;
typedef __attribute__((ext_vector_type(4)))  float f32x4;
typedef __attribute__((ext_vector_type(16))) float f32x16;

__device__ __forceinline__ uint32_t f2bf(float f) {
    uint32_t u = __builtin_bit_cast(uint32_t, f);
    return (u + 0x7FFFu + ((u >> 16) & 1u)) >> 16;   // RNE
}
__device__ __forceinline__ uint32_t pkbf2(float lo, float hi) {
    __hip_bfloat162 h = __float22bfloat162_rn(float2{lo, hi});
    uint32_t r; __builtin_memcpy(&r, &h, 4);         // v_cvt_pk_bf16_f32
    return r;
}

// ws layout (uint16): cls_Wh @0, box_Wh @65536, cls_Wo @131072, box_Wo(pad 16x256) @151552
#define WOFF_CWH 0
#define WOFF_BWH 65536
#define WOFF_CWO 131072
#define WOFF_BWO 151552

__global__ void prep_weights(const float* __restrict__ cWh, const float* __restrict__ cWo,
                             const float* __restrict__ bWh, const float* __restrict__ bWo,
                             uint16_t* __restrict__ ws) {
    int i = blockIdx.x * 256 + threadIdx.x;
    if (i >= 155648) return;
    uint32_t v;
    if (i < 65536)       v = f2bf(cWh[i]);
    else if (i < 131072) v = f2bf(bWh[i - 65536]);
    else if (i < 151552) v = f2bf(cWo[i - 131072]);
    else { int j = i - 151552; v = (j < 1024) ? f2bf(bWo[j]) : 0u; }
    ws[i] = (uint16_t)v;
}

__global__ __launch_bounds__(512, 4) void dfd_fused(
    const float* __restrict__ fm0, const float* __restrict__ fm1,
    const float* __restrict__ fm2, const float* __restrict__ fm3,
    const float* __restrict__ fm4,
    const float* __restrict__ cls_bh, const float* __restrict__ cls_bo,
    const float* __restrict__ box_bh, const float* __restrict__ box_bo,
    const uint16_t* __restrict__ wbf,
    float* __restrict__ out)
{
    // 64 KB overlay: Xs[64 t][256 f] then Hs[64 t][512 hh] per iteration
    __shared__ uint16_t LB[64 * 512];
    uint16_t* Xs = LB;
    uint16_t* Hs = LB;

    const int tid  = threadIdx.x;
    const int lane = tid & 63;
    const int w    = tid >> 6;          // wave 0..7
    const int r    = lane & 15;
    const int q    = lane >> 4;
    const int col  = lane & 31;
    const int hi   = lane >> 5;
    const int b    = blockIdx.y;

    // per-tile level lookup (64-token tiles never span levels)
    auto lookup = [&](int n0, const float*& fm, int& off, int& ls) {
        if      (n0 < 16384) { fm = fm0; off = 0;     ls = 7; }
        else if (n0 < 20480) { fm = fm1; off = 16384; ls = 6; }
        else if (n0 < 21504) { fm = fm2; off = 20480; ls = 5; }
        else if (n0 < 21760) { fm = fm3; off = 21504; ls = 4; }
        else                 { fm = fm4; off = 21760; ls = 3; }
    };

    float xr[32];   // prefetched X tile: lane=token, 32 features (w*4 + i*32 + e)
    auto load_x = [&](int tl) {
        const float* fmp; int offp, lsp;
        const int nn = tl * 64;
        lookup(nn, fmp, offp, lsp);
        const int hwp = 1 << (2 * lsp);
        const float* src = fmp + (size_t)b * 256 * hwp + (nn - offp) + lane;
        #pragma unroll
        for (int i = 0; i < 8; ++i) {
            const int f = w * 4 + i * 32;
            #pragma unroll
            for (int e = 0; e < 4; ++e)
                xr[i * 4 + e] = src[(size_t)(f + e) * hwp];
        }
    };

    const int base = blockIdx.x * NITER;
    load_x(base < NTILES ? base : NTILES - 1);

    for (int it = 0; it < NITER; ++it) {
        const int tile = base + it;
        if (tile >= NTILES) break;         // block-uniform exit
        const int n0 = tile * 64;
        const float* fmc; int off, ls;
        lookup(n0, fmc, off, ls);
        const int dim = 1 << ls;
        const int p0  = n0 - off;

        // ---- Xs write from prefetched regs (b64 swizzled)
        {
            const int t  = lane;
            const int sw = (t & 7) << 3;
            #pragma unroll
            for (int i = 0; i < 8; ++i) {
                const int f = w * 4 + i * 32;
                uint2 pk;
                pk.x = pkbf2(xr[i * 4 + 0], xr[i * 4 + 1]);
                pk.y = pkbf2(xr[i * 4 + 2], xr[i * 4 + 3]);
                *reinterpret_cast<uint2*>(&Xs[t * 256 + (f ^ sw)]) = pk;
            }
        }
        __syncthreads();

        // ---- prefetch next tile's X into regs (overlaps G1+epilogue+G2)
        if (it + 1 < NITER) {
            int nt_ = tile + 1;
            if (nt_ > NTILES - 1) nt_ = NTILES - 1;   // harmless clamp
            load_x(nt_);
        }

        // ---- G1 (32x32x16, both heads): wave w -> hidden cols [w*32, w*32+32)
        f32x16 acc[2][2];   // [mt = token 32-tile][head]
        {
            #pragma unroll
            for (int mt = 0; mt < 2; ++mt)
                #pragma unroll
                for (int h = 0; h < 2; ++h)
                    #pragma unroll
                    for (int e = 0; e < 16; ++e) acc[mt][h][e] = 0.f;

            const int rowoff = (w * 32 + col) * 256;
            const int kh = hi * 8;
            const uint16_t* Wc = wbf + WOFF_CWH + rowoff + kh;
            const uint16_t* Wb = wbf + WOFF_BWH + rowoff + kh;
            const int sw0 = (col & 7) << 3;

            #pragma unroll
            for (int ks = 0; ks < 16; ++ks) {
                const bf16x8 bc = *(const bf16x8*)(Wc + ks * 16);
                const bf16x8 bb = *(const bf16x8*)(Wb + ks * 16);
                const int kx = (ks * 16 + kh) ^ sw0;
                const bf16x8 x0 = *(const bf16x8*)&Xs[col * 256 + kx];
                const bf16x8 x1 = *(const bf16x8*)&Xs[(32 + col) * 256 + kx];
                acc[0][0] = __builtin_amdgcn_mfma_f32_32x32x16_bf16(x0, bc, acc[0][0], 0, 0, 0);
                acc[0][1] = __builtin_amdgcn_mfma_f32_32x32x16_bf16(x0, bb, acc[0][1], 0, 0, 0);
                acc[1][0] = __builtin_amdgcn_mfma_f32_32x32x16_bf16(x1, bc, acc[1][0], 0, 0, 0);
                acc[1][1] = __builtin_amdgcn_mfma_f32_32x32x16_bf16(x1, bb, acc[1][1], 0, 0, 0);
            }
        }
        __syncthreads();   // all Xs reads done before Hs overwrites

        // ---- epilogue: bias+ReLU, C[t][h] -> Hs[t][hh^sw] (round-5 verified layout)
        {
            const float bc  = cls_bh[w * 32 + col];
            const float bbx = box_bh[w * 32 + col];
            const int hh = w * 32 + col;
            #pragma unroll
            for (int mt = 0; mt < 2; ++mt) {
                #pragma unroll
                for (int reg = 0; reg < 16; ++reg) {
                    const int t  = mt * 32 + (reg & 3) + 8 * (reg >> 2) + 4 * hi;
                    const int sw = (t & 7) << 3;
                    Hs[t * 512 + ((hh)       ^ sw)] = (uint16_t)f2bf(fmaxf(acc[mt][0][reg] + bc,  0.f));
                    Hs[t * 512 + ((256 + hh) ^ sw)] = (uint16_t)f2bf(fmaxf(acc[mt][1][reg] + bbx, 0.f));
                }
            }
        }
        __syncthreads();

        // ---- G2 (16x16x32): waves 0-4 = cls out-tile w; waves 5,6 = box + decode
        if (w < 5) {
            f32x4 c[4];
            #pragma unroll
            for (int m = 0; m < 4; ++m) c[m] = {0.f, 0.f, 0.f, 0.f};
            const uint16_t* Bw = wbf + WOFF_CWO + (w * 16 + r) * 256 + q * 8;
            #pragma unroll
            for (int kq = 0; kq < 8; ++kq) {
                const bf16x8 bfr = *(const bf16x8*)(Bw + kq * 32);
                #pragma unroll
                for (int m = 0; m < 4; ++m) {
                    const int t = m * 16 + r;
                    const int kcol = (kq * 32 + q * 8) ^ ((t & 7) << 3);
                    const bf16x8 a = *(const bf16x8*)&Hs[t * 512 + kcol];
                    c[m] = __builtin_amdgcn_mfma_f32_16x16x32_bf16(a, bfr, c[m], 0, 0, 0);
                }
            }
            const float bo_l = cls_bo[w * 16 + r];
            #pragma unroll
            for (int m = 0; m < 4; ++m)
                #pragma unroll
                for (int jj = 0; jj < 4; ++jj)
                    out[((size_t)b * NTOK + n0 + m * 16 + q * 4 + jj) * 84 + w * 16 + r]
                        = c[m][jj] + bo_l;
        } else if (w < 7) {
            const int m0 = (w - 5) * 2;
            f32x4 c[2];
            c[0] = {0.f, 0.f, 0.f, 0.f}; c[1] = {0.f, 0.f, 0.f, 0.f};
            const uint16_t* Bw = wbf + WOFF_BWO + r * 256 + q * 8;
            #pragma unroll
            for (int kq = 0; kq < 8; ++kq) {
                const bf16x8 bfr = *(const bf16x8*)(Bw + kq * 32);
                #pragma unroll
                for (int mm = 0; mm < 2; ++mm) {
                    const int t = (m0 + mm) * 16 + r;
                    const int kcol = 256 + ((kq * 32 + q * 8) ^ ((t & 7) << 3));
                    const bf16x8 a = *(const bf16x8*)&Hs[t * 512 + kcol];
                    c[mm] = __builtin_amdgcn_mfma_f32_16x16x32_bf16(a, bfr, c[mm], 0, 0, 0);
                }
            }
            if (r < 4) {
                const float bo_l = box_bo[r];
                const float inv  = 1.0f / (float)dim;
                #pragma unroll
                for (int mm = 0; mm < 2; ++mm)
                    #pragma unroll
                    for (int jj = 0; jj < 4; ++jj) {
                        const int t = (m0 + mm) * 16 + q * 4 + jj;
                        const int p = p0 + t;
                        const float d = tanhf(c[mm][jj] + bo_l);
                        float val;
                        if (r == 0)      val = ((float)(p & (dim - 1)) + 0.5f) * inv + 0.1f * d;
                        else if (r == 1) val = ((float)(p >> ls) + 0.5f) * inv + 0.1f * d;
                        else             val = exp2f(d) * inv;
                        out[((size_t)b * NTOK + n0 + t) * 84 + 80 + r] = val;
                    }
            }
        }
        __syncthreads();   // G2's Hs reads done before next iteration's Xs write
    }
}

extern "C" void kernel_launch(void* const* d_in, const int* in_sizes, int n_in,
                              void* d_out, int out_size, void* d_ws, size_t ws_size,
                              hipStream_t stream) {
    uint16_t* ws = (uint16_t*)d_ws;
    prep_weights<<<608, 256, 0, stream>>>(
        (const float*)d_in[5],  (const float*)d_in[7],
        (const float*)d_in[9],  (const float*)d_in[11], ws);
    dim3 grid(GRIDX, 8);   // 86 x 8 blocks, each up to 4 consecutive tiles
    dfd_fused<<<grid, 512, 0, stream>>>(
        (const float*)d_in[0], (const float*)d_in[1], (const float*)d_in[2],
        (const float*)d_in[3], (const float*)d_in[4],
        (const float*)d_in[6],  (const float*)d_in[8],
        (const float*)d_in[10], (const float*)d_in[12],
        ws, (float*)d_out);
}

// Round 10
// 135.650 us; speedup vs baseline: 3.8472x; 3.8472x over previous
//
#include <hip/hip_runtime.h>
#include <hip/hip_bf16.h>
#include <math.h>
#include <stdint.h>

#define NTOK 21824

typedef __attribute__((ext_vector_type(8)))  short bf16x8;
typedef __attribute__((ext_vector_type(4)))  float f32x4;
typedef __attribute__((ext_vector_type(16))) float f32x16;

__device__ __forceinline__ uint32_t f2bf(float f) {
    uint32_t u = __builtin_bit_cast(uint32_t, f);
    return (u + 0x7FFFu + ((u >> 16) & 1u)) >> 16;   // RNE
}
__device__ __forceinline__ uint32_t pkbf2(float lo, float hi) {
    __hip_bfloat162 h = __float22bfloat162_rn(float2{lo, hi});
    uint32_t r; __builtin_memcpy(&r, &h, 4);         // v_cvt_pk_bf16_f32
    return r;
}

// ws layout (uint16): cls_Wh @0, box_Wh @65536, cls_Wo @131072, box_Wo(pad 16x256) @151552
#define WOFF_CWH 0
#define WOFF_BWH 65536
#define WOFF_CWO 131072
#define WOFF_BWO 151552

__global__ void prep_weights(const float* __restrict__ cWh, const float* __restrict__ cWo,
                             const float* __restrict__ bWh, const float* __restrict__ bWo,
                             uint16_t* __restrict__ ws) {
    int i = blockIdx.x * 256 + threadIdx.x;
    if (i >= 155648) return;
    uint32_t v;
    if (i < 65536)       v = f2bf(cWh[i]);
    else if (i < 131072) v = f2bf(bWh[i - 65536]);
    else if (i < 151552) v = f2bf(cWo[i - 131072]);
    else { int j = i - 151552; v = (j < 1024) ? f2bf(bWo[j]) : 0u; }
    ws[i] = (uint16_t)v;
}

__global__ __launch_bounds__(512, 4) void dfd_fused(
    const float* __restrict__ fm0, const float* __restrict__ fm1,
    const float* __restrict__ fm2, const float* __restrict__ fm3,
    const float* __restrict__ fm4,
    const float* __restrict__ cls_bh, const float* __restrict__ cls_bo,
    const float* __restrict__ box_bh, const float* __restrict__ box_bo,
    const uint16_t* __restrict__ wbf,
    float* __restrict__ out)
{
    // 64 KB overlay: Xs[64 t][256 f] (phase 1-2) then Hs[64 t][512 hh] (phase 3-4)
    __shared__ uint16_t LB[64 * 512];
    uint16_t* Xs = LB;
    uint16_t* Hs = LB;

    const int tid  = threadIdx.x;
    const int lane = tid & 63;
    const int w    = tid >> 6;          // wave 0..7
    const int r    = lane & 15;
    const int q    = lane >> 4;
    const int col  = lane & 31;
    const int hi   = lane >> 5;
    const int n0   = blockIdx.x * 64;
    const int b    = blockIdx.y;

    const float* fm; int off, ls;
    if      (n0 < 16384) { fm = fm0; off = 0;     ls = 7; }
    else if (n0 < 20480) { fm = fm1; off = 16384; ls = 6; }
    else if (n0 < 21504) { fm = fm2; off = 20480; ls = 5; }
    else if (n0 < 21760) { fm = fm3; off = 21504; ls = 4; }
    else                 { fm = fm4; off = 21760; ls = 3; }
    const int dim = 1 << ls;
    const int hw  = dim * dim;
    const int p0  = n0 - off;

    // ---- stage: fm[b][f][p0+t] -> Xs[t][f^sw] bf16, packed b128 writes
    {
        const int t  = lane;
        const int sw = (t & 7) << 3;
        const float* src = fm + (size_t)b * 256 * hw + p0 + t;
        #pragma unroll
        for (int i = 0; i < 4; ++i) {
            const int f0 = w * 8 + i * 64;   // 8 consecutive features, 8-aligned
            float x[8];
            #pragma unroll
            for (int e = 0; e < 8; ++e) x[e] = src[(size_t)(f0 + e) * hw];
            uint4 pk;
            pk.x = pkbf2(x[0], x[1]); pk.y = pkbf2(x[2], x[3]);
            pk.z = pkbf2(x[4], x[5]); pk.w = pkbf2(x[6], x[7]);
            *reinterpret_cast<uint4*>(&Xs[t * 256 + (f0 ^ sw)]) = pk;   // swizzle keeps 8-run
        }
    }
    __syncthreads();

    // ---- G1 (32x32x16): C[h][t]. Wave w owns hh in [w*64, w*64+64) of the unified
    //      space (hh<256 = cls hidden, hh>=256 = box hidden). Verified in round 7.
    f32x16 acc[2][2];   // [mt = hh 32-tile][nt = token 32-tile]
    {
        #pragma unroll
        for (int mt = 0; mt < 2; ++mt)
            #pragma unroll
            for (int nt = 0; nt < 2; ++nt)
                #pragma unroll
                for (int e = 0; e < 16; ++e) acc[mt][nt][e] = 0.f;

        const int hh0 = w * 64;
        const uint16_t* Wbase = (w < 4) ? wbf + WOFF_CWH + hh0 * 256
                                        : wbf + WOFF_BWH + (hh0 - 256) * 256;
        const int kh = hi * 8;
        const uint16_t* Wr = Wbase + col * 256 + kh;   // A row = hh0 + mt*32 + col
        const int sw0 = (col & 7) << 3;                // (32+col)&7 == col&7

        #pragma unroll
        for (int ks = 0; ks < 16; ++ks) {
            const bf16x8 a0 = *(const bf16x8*)(Wr + ks * 16);
            const bf16x8 a1 = *(const bf16x8*)(Wr + 8192 + ks * 16);
            const int kx = (ks * 16 + kh) ^ sw0;
            const bf16x8 x0 = *(const bf16x8*)&Xs[col * 256 + kx];
            const bf16x8 x1 = *(const bf16x8*)&Xs[(32 + col) * 256 + kx];
            acc[0][0] = __builtin_amdgcn_mfma_f32_32x32x16_bf16(a0, x0, acc[0][0], 0, 0, 0);
            acc[0][1] = __builtin_amdgcn_mfma_f32_32x32x16_bf16(a0, x1, acc[0][1], 0, 0, 0);
            acc[1][0] = __builtin_amdgcn_mfma_f32_32x32x16_bf16(a1, x0, acc[1][0], 0, 0, 0);
            acc[1][1] = __builtin_amdgcn_mfma_f32_32x32x16_bf16(a1, x1, acc[1][1], 0, 0, 0);
        }
    }
    __syncthreads();   // all Xs reads done before Hs overwrites

    // ---- epilogue: bias+ReLU, pack 4 consecutive hh per b64 write (round-7 verified)
    {
        const int hh0 = w * 64;
        const float* bh_ = (w < 4) ? cls_bh + hh0 : box_bh + (hh0 - 256);
        #pragma unroll
        for (int mt = 0; mt < 2; ++mt) {
            #pragma unroll
            for (int nt = 0; nt < 2; ++nt) {
                const int t   = nt * 32 + col;
                const int swt = (t & 7) << 3;
                #pragma unroll
                for (int g = 0; g < 4; ++g) {
                    const int hb = mt * 32 + 8 * g + 4 * hi;   // C row = hb + (reg&3)
                    const f32x4 bv = *(const f32x4*)(bh_ + hb);
                    const float v0 = fmaxf(acc[mt][nt][4 * g + 0] + bv[0], 0.f);
                    const float v1 = fmaxf(acc[mt][nt][4 * g + 1] + bv[1], 0.f);
                    const float v2 = fmaxf(acc[mt][nt][4 * g + 2] + bv[2], 0.f);
                    const float v3 = fmaxf(acc[mt][nt][4 * g + 3] + bv[3], 0.f);
                    uint2 pk; pk.x = pkbf2(v0, v1); pk.y = pkbf2(v2, v3);
                    *reinterpret_cast<uint2*>(&Hs[t * 512 + ((hh0 + hb) ^ swt)]) = pk;
                }
            }
        }
    }
    __syncthreads();

    // ---- G2 (16x16x32): waves 0-4 = cls out-tile w; waves 5,6 = box + decode
    //      (round-5 verified, byte-identical)
    if (w < 5) {
        f32x4 c[4];
        #pragma unroll
        for (int m = 0; m < 4; ++m) c[m] = {0.f, 0.f, 0.f, 0.f};
        const uint16_t* Bw = wbf + WOFF_CWO + (w * 16 + r) * 256 + q * 8;
        #pragma unroll
        for (int kq = 0; kq < 8; ++kq) {
            const bf16x8 bfr = *(const bf16x8*)(Bw + kq * 32);
            #pragma unroll
            for (int m = 0; m < 4; ++m) {
                const int t = m * 16 + r;
                const int kcol = (kq * 32 + q * 8) ^ ((t & 7) << 3);
                const bf16x8 a = *(const bf16x8*)&Hs[t * 512 + kcol];
                c[m] = __builtin_amdgcn_mfma_f32_16x16x32_bf16(a, bfr, c[m], 0, 0, 0);
            }
        }
        const float bo_l = cls_bo[w * 16 + r];
        #pragma unroll
        for (int m = 0; m < 4; ++m)
            #pragma unroll
            for (int jj = 0; jj < 4; ++jj)
                out[((size_t)b * NTOK + n0 + m * 16 + q * 4 + jj) * 84 + w * 16 + r]
                    = c[m][jj] + bo_l;
    } else if (w < 7) {
        const int m0 = (w - 5) * 2;
        f32x4 c[2];
        c[0] = {0.f, 0.f, 0.f, 0.f}; c[1] = {0.f, 0.f, 0.f, 0.f};
        const uint16_t* Bw = wbf + WOFF_BWO + r * 256 + q * 8;
        #pragma unroll
        for (int kq = 0; kq < 8; ++kq) {
            const bf16x8 bfr = *(const bf16x8*)(Bw + kq * 32);
            #pragma unroll
            for (int mm = 0; mm < 2; ++mm) {
                const int t = (m0 + mm) * 16 + r;
                const int kcol = 256 + ((kq * 32 + q * 8) ^ ((t & 7) << 3));
                const bf16x8 a = *(const bf16x8*)&Hs[t * 512 + kcol];
                c[mm] = __builtin_amdgcn_mfma_f32_16x16x32_bf16(a, bfr, c[mm], 0, 0, 0);
            }
        }
        if (r < 4) {
            const float bo_l = box_bo[r];
            const float inv  = 1.0f / (float)dim;
            #pragma unroll
            for (int mm = 0; mm < 2; ++mm)
                #pragma unroll
                for (int jj = 0; jj < 4; ++jj) {
                    const int t = (m0 + mm) * 16 + q * 4 + jj;
                    const int p = p0 + t;
                    const float d = tanhf(c[mm][jj] + bo_l);
                    float val;
                    if (r == 0)      val = ((float)(p & (dim - 1)) + 0.5f) * inv + 0.1f * d;
                    else if (r == 1) val = ((float)(p >> ls) + 0.5f) * inv + 0.1f * d;
                    else             val = exp2f(d) * inv;
                    out[((size_t)b * NTOK + n0 + t) * 84 + 80 + r] = val;
                }
        }
    }
}

extern "C" void kernel_launch(void* const* d_in, const int* in_sizes, int n_in,
                              void* d_out, int out_size, void* d_ws, size_t ws_size,
                              hipStream_t stream) {
    uint16_t* ws = (uint16_t*)d_ws;
    prep_weights<<<608, 256, 0, stream>>>(
        (const float*)d_in[5],  (const float*)d_in[7],
        (const float*)d_in[9],  (const float*)d_in[11], ws);
    dim3 grid(NTOK / 64, 8);   // 341 x 8 blocks, 512 threads, one tile each
    dfd_fused<<<grid, 512, 0, stream>>>(
        (const float*)d_in[0], (const float*)d_in[1], (const float*)d_in[2],
        (const float*)d_in[3], (const float*)d_in[4],
        (const float*)d_in[6],  (const float*)d_in[8],
        (const float*)d_in[10], (const float*)d_in[12],
        ws, (float*)d_out);
}